// Round 2
// baseline (443.549 us; speedup 1.0000x reference)
//
#include <hip/hip_runtime.h>
#include <hip/hip_bf16.h>
#include <hip/hip_cooperative_groups.h>

namespace cg = cooperative_groups;

// Sparse MoE: T=2048, D=1024, E=8 routed (H=768, top-2) + shared GatedMLP (1536 hidden).
// R9: single cooperative persistent kernel (3 blocks/CU, 48KB LDS, 2 grid.sync()).
//   Phase A: convert W1/Ws1 + gate (x-conv, routing, out-zero).
//   Phase B: work-queue { 864 fc1 tiles (M128xN64y+N64g, BK64, round-0 form) +
//            960 W2/Ws2 conversion items } -- conversion overlaps fc1 + fills tail.
//   Phase C: work-queue fc2 tiles (M128xN64, BK128, round-0 form), shared-heavy first.
// Eliminates 2 kernel launches, the fc1->W2-conversion false dependency, and dispatch
// tail raggedness. GEMM tile bodies are the round-0 proven versions (R8 post-mortem:
// intra-kernel dbuf was neutral-to-negative; the serialization between kernels is the
// remaining cost).

typedef short bf16x8 __attribute__((ext_vector_type(8)));
typedef float f32x4 __attribute__((ext_vector_type(4)));

__device__ __forceinline__ unsigned short f2b(float f) {
    __hip_bfloat16 h = __float2bfloat16(f);
    return *reinterpret_cast<unsigned short*>(&h);
}

__device__ __forceinline__ void ldst16(const unsigned short* g, unsigned short* l) {
    __builtin_amdgcn_global_load_lds(
        (const __attribute__((address_space(1))) unsigned int*)g,
        (__attribute__((address_space(3))) unsigned int*)l, 16, 0, 0);
}

__device__ __forceinline__ void cvt8(const float* s, unsigned short* d, int j) {
    const float4* sp = reinterpret_cast<const float4*>(s) + (size_t)j * 2;
    float4 v0 = sp[0], v1 = sp[1];
    union { unsigned short u[8]; uint4 v; } o;
    o.u[0]=f2b(v0.x); o.u[1]=f2b(v0.y); o.u[2]=f2b(v0.z); o.u[3]=f2b(v0.w);
    o.u[4]=f2b(v1.x); o.u[5]=f2b(v1.y); o.u[6]=f2b(v1.z); o.u[7]=f2b(v1.w);
    *(reinterpret_cast<uint4*>(d) + j) = o.v;
}

// ---------- fc1 tile: M128 x (N64 y | N64 g), BK=64, single-buffered 32KB ----------
__device__ void fc1_tile(int tile, unsigned short* smem,
                         const unsigned short* __restrict__ xb,
                         const unsigned short* __restrict__ W1b,
                         const unsigned short* __restrict__ Ws1b,
                         const int* __restrict__ tokslot,
                         const float* __restrict__ wroute,
                         const int* __restrict__ cnt,
                         unsigned short* __restrict__ act_r,
                         unsigned short* __restrict__ acts)
{
    unsigned short* As = smem;           // 128*64 = 8192 ushort (16KB)
    unsigned short* Bs = smem + 8192;    // 128*64 = 8192 ushort (16KB)
    const int tid = threadIdx.x, lane = tid & 63, w = tid >> 6;
    const int wr = w >> 1, wc = w & 1;
    const int mt = tile / 12, ht = tile % 12;

    int pre = 0, sel = -1, base = 0;
    for (int ee = 0; ee < 10; ee++) {
        int til = (ee < 8) ? ((cnt[ee * 16] + 127) >> 7) : 16;
        if (sel < 0 && mt < pre + til) { sel = ee; base = pre; }
        pre += til;
    }
    if (sel < 0) return;
    const int e = sel, m0 = (mt - base) * 128, h0 = ht * 64;
    const int Te = (e < 8) ? cnt[e * 16] : 2048;
    const unsigned short* Bp = (e < 8) ? (W1b + (size_t)e * 1536 * 1024)
                                       : (Ws1b + (size_t)(e - 8) * 768 * 1024);
    const int gOff = (e < 8) ? 768 : 1536;

    const int kc = tid & 7;
    int aoff[4], boff[4];
    for (int q = 0; q < 4; q++) {
        int row = q * 32 + (tid >> 3);                 // 0..127
        int idx = m0 + row;
        int tk = (e < 8) ? ((idx < Te) ? tokslot[e * 2048 + idx] : 0) : idx;
        aoff[q] = tk * 1024 + ((kc ^ (row & 7)) << 3);
        int grow = (row < 64) ? (h0 + row) : (gOff + h0 + row - 64);
        boff[q] = grow * 1024 + ((kc ^ (row & 7)) << 3);
    }

    f32x4 accy[4][2], accg[4][2];
    for (int i = 0; i < 4; i++)
        for (int j = 0; j < 2; j++) {
            accy[i][j] = (f32x4){0.f, 0.f, 0.f, 0.f};
            accg[i][j] = (f32x4){0.f, 0.f, 0.f, 0.f};
        }

    for (int k0 = 0; k0 < 1024; k0 += 64) {
        for (int q = 0; q < 4; q++) {
            ldst16(xb + aoff[q] + k0, As + (q * 256 + tid) * 8);
            ldst16(Bp + boff[q] + k0, Bs + (q * 256 + tid) * 8);
        }
        __syncthreads();
        for (int kh = 0; kh < 2; kh++) {
            const int cq = kh * 4 + (lane >> 4);
            bf16x8 a[4], by[2], bg[2];
            for (int i = 0; i < 4; i++) {
                int r = 64 * wr + 16 * i + (lane & 15);
                a[i] = *(const bf16x8*)&As[r * 64 + ((cq ^ (r & 7)) << 3)];
            }
            for (int j = 0; j < 2; j++) {
                int ry = 32 * wc + 16 * j + (lane & 15);
                by[j] = *(const bf16x8*)&Bs[ry * 64 + ((cq ^ (ry & 7)) << 3)];
                int rg = 64 + ry;
                bg[j] = *(const bf16x8*)&Bs[rg * 64 + ((cq ^ (rg & 7)) << 3)];
            }
            __builtin_amdgcn_s_setprio(1);
            for (int i = 0; i < 4; i++)
                for (int j = 0; j < 2; j++) {
                    accy[i][j] = __builtin_amdgcn_mfma_f32_16x16x32_bf16(a[i], by[j], accy[i][j], 0, 0, 0);
                    accg[i][j] = __builtin_amdgcn_mfma_f32_16x16x32_bf16(a[i], bg[j], accg[i][j], 0, 0, 0);
                }
            __builtin_amdgcn_s_setprio(0);
        }
        __syncthreads();
    }

    for (int i = 0; i < 4; i++)
        for (int r = 0; r < 4; r++) {
            int irow = m0 + 64 * wr + 16 * i + ((lane >> 4) << 2) + r;
            if (irow >= Te) continue;
            float sw = (e < 8) ? wroute[e * 2048 + irow] : 1.0f;
            unsigned short* dst = (e < 8)
                ? (act_r + ((size_t)e * 2048 + irow) * 768)
                : (acts + (size_t)irow * 1536 + (size_t)(e - 8) * 768);
            for (int j = 0; j < 2; j++) {
                float y = accy[i][j][r], g = accg[i][j][r];
                float sg = g / (1.0f + __expf(-g));
                int col = h0 + 32 * wc + 16 * j + (lane & 15);
                dst[col] = f2b(sw * y * sg);
            }
        }
}

// ---------- fc2 tile: M128 x N64, BK=128, single-buffered 48KB, atomicAdd out ------
__device__ void fc2_tile(int tile, unsigned short* smem,
                         const unsigned short* __restrict__ act_r,
                         const unsigned short* __restrict__ acts,
                         const unsigned short* __restrict__ W2b,
                         const unsigned short* __restrict__ Ws2b,
                         const int* __restrict__ tokslot,
                         const int* __restrict__ cnt,
                         float* __restrict__ out)
{
    unsigned short* As = smem;            // 128*128 = 16384 ushort (32KB)
    unsigned short* Bs = smem + 16384;    //  64*128 =  8192 ushort (16KB)
    const int tid = threadIdx.x, lane = tid & 63, w = tid >> 6;
    const int wr = w >> 1, wc = w & 1;
    const int mt = tile >> 4, nt = tile & 15;

    int pre = 0, sel = -1, base = 0;
    for (int ee = 0; ee < 9; ee++) {
        int til = (ee < 8) ? ((cnt[ee * 16] + 127) >> 7) : 16;
        if (sel < 0 && mt < pre + til) { sel = ee; base = pre; }
        pre += til;
    }
    if (sel < 0) return;
    const int e = sel, m0 = (mt - base) * 128, n0 = nt * 64;
    int Te, astride, bstride, K;
    const unsigned short *Ab, *Bb;
    if (e < 8) {
        Te = cnt[e * 16]; K = 768; astride = 768; bstride = 768;
        Ab = act_r + (size_t)e * 2048 * 768;
        Bb = W2b + (size_t)e * 1024 * 768;
    } else {
        Te = 2048; K = 1536; astride = 1536; bstride = 1536;
        Ab = acts;
        Bb = Ws2b;
    }

    const int cp = tid & 15;
    int aoff[8], boff[4];
    for (int q = 0; q < 8; q++) {
        int row = q * 16 + (tid >> 4);                 // 0..127
        aoff[q] = (m0 + row) * astride + ((cp ^ (row & 15)) << 3);
    }
    for (int q = 0; q < 4; q++) {
        int row = q * 16 + (tid >> 4);                 // 0..63
        boff[q] = (n0 + row) * bstride + ((cp ^ (row & 15)) << 3);
    }

    f32x4 acc[4][2];
    for (int i = 0; i < 4; i++)
        for (int j = 0; j < 2; j++) acc[i][j] = (f32x4){0.f, 0.f, 0.f, 0.f};

    for (int k0 = 0; k0 < K; k0 += 128) {
        for (int q = 0; q < 8; q++) ldst16(Ab + aoff[q] + k0, As + (q * 256 + tid) * 8);
        for (int q = 0; q < 4; q++) ldst16(Bb + boff[q] + k0, Bs + (q * 256 + tid) * 8);
        __syncthreads();
        for (int kh = 0; kh < 4; kh++) {
            const int cq = kh * 4 + (lane >> 4);
            bf16x8 a[4], b[2];
            for (int i = 0; i < 4; i++) {
                int r = 64 * wr + 16 * i + (lane & 15);
                a[i] = *(const bf16x8*)&As[r * 128 + ((cq ^ (r & 15)) << 3)];
            }
            for (int j = 0; j < 2; j++) {
                int rb = 32 * wc + 16 * j + (lane & 15);
                b[j] = *(const bf16x8*)&Bs[rb * 128 + ((cq ^ (rb & 15)) << 3)];
            }
            __builtin_amdgcn_s_setprio(1);
            for (int i = 0; i < 4; i++)
                for (int j = 0; j < 2; j++)
                    acc[i][j] = __builtin_amdgcn_mfma_f32_16x16x32_bf16(a[i], b[j], acc[i][j], 0, 0, 0);
            __builtin_amdgcn_s_setprio(0);
        }
        __syncthreads();
    }

    for (int i = 0; i < 4; i++)
        for (int r = 0; r < 4; r++) {
            int irow = m0 + 64 * wr + 16 * i + ((lane >> 4) << 2) + r;
            if (irow >= Te) continue;
            int t = (e < 8) ? tokslot[e * 2048 + irow] : irow;
            for (int j = 0; j < 2; j++) {
                int col = n0 + 32 * wc + 16 * j + (lane & 15);
                atomicAdd(out + (size_t)t * 1024 + col, acc[i][j][r]);
            }
        }
}

// --------------------------- the single cooperative kernel -------------------------
__global__ __launch_bounds__(256, 3) void k_moe(
    const float* __restrict__ x, const float* __restrict__ gw,
    const float* __restrict__ W1, const float* __restrict__ Ws1,
    const float* __restrict__ W2, const float* __restrict__ Ws2,
    unsigned short* __restrict__ xb, unsigned short* __restrict__ W1b,
    unsigned short* __restrict__ Ws1b, unsigned short* __restrict__ W2b,
    unsigned short* __restrict__ Ws2b, int* __restrict__ tokslot,
    float* __restrict__ wroute, int* __restrict__ cnt,
    unsigned short* __restrict__ act_r, unsigned short* __restrict__ acts,
    float* __restrict__ out)
{
    __shared__ alignas(16) unsigned short smem[24576];   // 48KB, reused per phase
    const int tid = threadIdx.x, bid = blockIdx.x, nb = gridDim.x;
    cg::grid_group grid = cg::this_grid();

    // ===== Phase A: convert W1/Ws1 (grid-stride) + gate/x-conv/out-zero ============
    {
        const int stride = nb * 256;
        for (int i = bid * 256 + tid; i < 1966080; i += stride) {
            if (i < 1572864) cvt8(W1, W1b, i);
            else             cvt8(Ws1, Ws1b, i - 1572864);
        }
        const int lane = tid & 63, w = tid >> 6;
        float* red = (float*)smem;     // [4][8]
        float* sc  = red + 32;         // [8]
        for (int t = bid; t < 2048; t += nb) {
            float4 v = reinterpret_cast<const float4*>(x + (size_t)t * 1024)[tid];
            union { unsigned short u[4]; ushort4 v4; } o;
            o.u[0]=f2b(v.x); o.u[1]=f2b(v.y); o.u[2]=f2b(v.z); o.u[3]=f2b(v.w);
            reinterpret_cast<ushort4*>(xb + (size_t)t * 1024)[tid] = o.v4;

            float p[8];
            for (int e = 0; e < 8; e++) {
                float4 g = reinterpret_cast<const float4*>(gw + (size_t)e * 1024)[tid];
                p[e] = v.x*g.x + v.y*g.y + v.z*g.z + v.w*g.w;
            }
            for (int e = 0; e < 8; e++)
                for (int off = 32; off > 0; off >>= 1) p[e] += __shfl_down(p[e], off, 64);
            if (lane == 0)
                for (int e = 0; e < 8; e++) red[w * 8 + e] = p[e];
            __syncthreads();
            if (tid < 8) sc[tid] = red[tid] + red[8 + tid] + red[16 + tid] + red[24 + tid];
            __syncthreads();
            if (tid == 0) {
                float m = sc[0];
                for (int e = 1; e < 8; e++) m = fmaxf(m, sc[e]);
                float ex[8], sum = 0.f;
                for (int e = 0; e < 8; e++) { ex[e] = expf(sc[e] - m); sum += ex[e]; }
                float inv = 1.f / sum;
                int i1 = 0;
                for (int e = 1; e < 8; e++) if (sc[e] > sc[i1]) i1 = e;
                int i2 = -1; float s2 = -1e30f;
                for (int e = 0; e < 8; e++) if (e != i1 && sc[e] > s2) { s2 = sc[e]; i2 = e; }
                int p1 = atomicAdd(&cnt[i1 * 16], 1);          // 64B-padded counters
                tokslot[i1 * 2048 + p1] = t; wroute[i1 * 2048 + p1] = ex[i1] * inv;
                int p2 = atomicAdd(&cnt[i2 * 16], 1);
                tokslot[i2 * 2048 + p2] = t; wroute[i2 * 2048 + p2] = ex[i2] * inv;
            }
            reinterpret_cast<float4*>(out + (size_t)t * 1024)[tid] = (float4){0.f, 0.f, 0.f, 0.f};
            __syncthreads();   // sc reused next loop iteration
        }
    }
    __threadfence();
    grid.sync();

    // ===== Phase B: queue { fc1 tiles [0,864) | W2/Ws2 conv items [864,1824) } =====
    {
        int* bc = (int*)smem;
        while (true) {
            if (tid == 0) *bc = atomicAdd(cnt + 120, 1);
            __syncthreads();
            const int item = *bc;
            __syncthreads();                 // all read bc before smem is re-staged
            if (item >= 1824) break;
            if (item < 864) {
                fc1_tile(item, smem, xb, W1b, Ws1b, tokslot, wroute, cnt, act_r, acts);
            } else {
                const int c0 = (item - 864) * 1024 + tid;   // 1024 cvt8-chunks per item
                #pragma unroll
                for (int u = 0; u < 4; u++) {
                    int i = c0 + u * 256;
                    if (i < 786432)       cvt8(W2, W2b, i);
                    else                  cvt8(Ws2, Ws2b, i - 786432);   // i < 983040
                }
            }
        }
    }
    __threadfence();
    grid.sync();

    // ===== Phase C: queue fc2 tiles, reversed so shared-expert (K=1536) run first ==
    {
        int* bc = (int*)smem;
        while (true) {
            if (tid == 0) *bc = atomicAdd(cnt + 124, 1);
            __syncthreads();
            const int item = *bc;
            __syncthreads();
            if (item >= 896) break;
            fc2_tile(895 - item, smem, act_r, acts, W2b, Ws2b, tokslot, cnt, out);
        }
    }
}

extern "C" void kernel_launch(void* const* d_in, const int* in_sizes, int n_in,
                              void* d_out, int out_size, void* d_ws, size_t ws_size,
                              hipStream_t stream) {
    const float* x   = (const float*)d_in[0];
    const float* gw  = (const float*)d_in[1];
    const float* W1  = (const float*)d_in[2];
    const float* W2  = (const float*)d_in[3];
    const float* Ws1 = (const float*)d_in[4];
    const float* Ws2 = (const float*)d_in[5];
    float* out = (float*)d_out;

    char* ws = (char*)d_ws;
    unsigned short* xb    = (unsigned short*)(ws + 0);          //  4,194,304
    unsigned short* W1b   = (unsigned short*)(ws + 4194304);    // 25,165,824
    unsigned short* Ws1b  = (unsigned short*)(ws + 29360128);   //  6,291,456
    unsigned short* W2b   = (unsigned short*)(ws + 35651584);   // 12,582,912
    unsigned short* Ws2b  = (unsigned short*)(ws + 48234496);   //  3,145,728
    unsigned short* act_r = (unsigned short*)(ws + 51380224);   // 25,165,824 (8x2048x768)
    unsigned short* acts  = (unsigned short*)(ws + 76546048);   //  6,291,456 (2048x1536)
    int*            tokslot = (int*)(ws + 82837504);            //     65,536 (8x2048)
    float*          wroute  = (float*)(ws + 82903040);          //     65,536
    int*            cnt     = (int*)(ws + 82968576);            //        512 (8x16 ints;
                                                                //  [120],[124] = queues)

    // grid = min(occupancy, 3) blocks/CU * 256 CUs; all phase loops are grid-agnostic.
    static int gridsz = 0;
    if (gridsz == 0) {
        int nbpc = 0;
        if (hipOccupancyMaxActiveBlocksPerMultiprocessor(&nbpc, k_moe, 256, 0) != hipSuccess
            || nbpc < 1) nbpc = 1;
        if (nbpc > 3) nbpc = 3;
        gridsz = nbpc * 256;
    }

    hipMemsetAsync(cnt, 0, 512, stream);
    void* args[] = {(void*)&x, (void*)&gw, (void*)&W1, (void*)&Ws1, (void*)&W2, (void*)&Ws2,
                    (void*)&xb, (void*)&W1b, (void*)&Ws1b, (void*)&W2b, (void*)&Ws2b,
                    (void*)&tokslot, (void*)&wroute, (void*)&cnt,
                    (void*)&act_r, (void*)&acts, (void*)&out};
    hipLaunchCooperativeKernel((void*)k_moe, dim3(gridsz), dim3(256), args, 0, stream);
}

// Round 3
// 243.996 us; speedup vs baseline: 1.8179x; 1.8179x over previous
//
#include <hip/hip_runtime.h>
#include <hip/hip_bf16.h>

// Sparse MoE: T=2048, D=1024, E=8 routed (H=768, top-2) + shared GatedMLP (1536 hidden).
// R10: revert to R0 3-kernel structure (R9 coop mega-kernel regressed 2x: uniform 48KB
// LDS strangled streaming-phase occupancy). Changes vs R0:
//  - fc1/fc2: mt-granular XCD swizzle (xcd=bid%8; mt=(bid/8/HT)*8+xcd; ht=bid/8%HT) so
//    each mt's tiles share one XCD's L2 (A-panel + expert B-set resident) while active
//    mts stay balanced across XCDs (contiguous chunking would idle 2-3 XCDs since the
//    tail mt-slots early-exit).
//  - convgate: conversion does 2 independent chunks/thread (2x MLP), 5760 conv blocks.

typedef short bf16x8 __attribute__((ext_vector_type(8)));
typedef float f32x4 __attribute__((ext_vector_type(4)));

__device__ __forceinline__ unsigned short f2b(float f) {
    __hip_bfloat16 h = __float2bfloat16(f);
    return *reinterpret_cast<unsigned short*>(&h);
}

__device__ __forceinline__ void ldst16(const unsigned short* g, unsigned short* l) {
    __builtin_amdgcn_global_load_lds(
        (const __attribute__((address_space(1))) unsigned int*)g,
        (__attribute__((address_space(3))) unsigned int*)l, 16, 0, 0);
}

__device__ __forceinline__ void cvt8(const float* s, unsigned short* d, int j) {
    const float4* sp = reinterpret_cast<const float4*>(s) + (size_t)j * 2;
    float4 v0 = sp[0], v1 = sp[1];
    union { unsigned short u[8]; uint4 v; } o;
    o.u[0]=f2b(v0.x); o.u[1]=f2b(v0.y); o.u[2]=f2b(v0.z); o.u[3]=f2b(v0.w);
    o.u[4]=f2b(v1.x); o.u[5]=f2b(v1.y); o.u[6]=f2b(v1.z); o.u[7]=f2b(v1.w);
    *(reinterpret_cast<uint4*>(d) + j) = o.v;
}

__device__ __forceinline__ void cvt_dispatch(const float* W1, const float* Ws1,
                                             const float* W2, const float* Ws2,
                                             unsigned short* W1b, unsigned short* Ws1b,
                                             unsigned short* W2b, unsigned short* Ws2b,
                                             int i) {
    if (i < 1572864)       cvt8(W1,  W1b,  i);
    else if (i < 1966080)  cvt8(Ws1, Ws1b, i - 1572864);
    else if (i < 2752512)  cvt8(W2,  W2b,  i - 1966080);
    else if (i < 2949120)  cvt8(Ws2, Ws2b, i - 2752512);
}

// ------- merged: weight conversion (blocks 0..5759, 2 chunks/thread) + gate ----------
__global__ __launch_bounds__(256) void k_convgate(const float* __restrict__ x,
                                                  const float* __restrict__ gw,
                                                  const float* __restrict__ W1,
                                                  const float* __restrict__ Ws1,
                                                  const float* __restrict__ W2,
                                                  const float* __restrict__ Ws2,
                                                  unsigned short* __restrict__ xb,
                                                  unsigned short* __restrict__ W1b,
                                                  unsigned short* __restrict__ Ws1b,
                                                  unsigned short* __restrict__ W2b,
                                                  unsigned short* __restrict__ Ws2b,
                                                  int* __restrict__ tokslot,
                                                  float* __restrict__ wroute,
                                                  int* __restrict__ cnt,
                                                  float* __restrict__ out) {
    __shared__ float red[4][8];
    __shared__ float sc[8];
    const int b = blockIdx.x, tid = threadIdx.x;
    if (b < 5760) {
        int i0 = b * 512 + tid;     // two coalesced chunks, independent loads
        cvt_dispatch(W1, Ws1, W2, Ws2, W1b, Ws1b, W2b, Ws2b, i0);
        cvt_dispatch(W1, Ws1, W2, Ws2, W1b, Ws1b, W2b, Ws2b, i0 + 256);
        return;
    }
    // ---- gate: one token per block, fully coalesced ----
    const int t = b - 5760;
    const int lane = tid & 63, w = tid >> 6;

    float4 v = reinterpret_cast<const float4*>(x + (size_t)t * 1024)[tid];
    union { unsigned short u[4]; } o;
    o.u[0]=f2b(v.x); o.u[1]=f2b(v.y); o.u[2]=f2b(v.z); o.u[3]=f2b(v.w);
    reinterpret_cast<ushort4*>(xb + (size_t)t * 1024)[tid] = *(ushort4*)o.u;

    float p[8];
    for (int e = 0; e < 8; e++) {
        float4 g = reinterpret_cast<const float4*>(gw + (size_t)e * 1024)[tid];
        p[e] = v.x*g.x + v.y*g.y + v.z*g.z + v.w*g.w;
    }
    for (int e = 0; e < 8; e++)
        for (int off = 32; off > 0; off >>= 1) p[e] += __shfl_down(p[e], off, 64);
    if (lane == 0)
        for (int e = 0; e < 8; e++) red[w][e] = p[e];
    __syncthreads();
    if (tid < 8) sc[tid] = red[0][tid] + red[1][tid] + red[2][tid] + red[3][tid];
    __syncthreads();
    if (tid == 0) {
        float m = sc[0];
        for (int e = 1; e < 8; e++) m = fmaxf(m, sc[e]);
        float ex[8], sum = 0.f;
        for (int e = 0; e < 8; e++) { ex[e] = expf(sc[e] - m); sum += ex[e]; }
        float inv = 1.f / sum;
        int i1 = 0;
        for (int e = 1; e < 8; e++) if (sc[e] > sc[i1]) i1 = e;
        int i2 = -1; float s2 = -1e30f;
        for (int e = 0; e < 8; e++) if (e != i1 && sc[e] > s2) { s2 = sc[e]; i2 = e; }
        int p1 = atomicAdd(&cnt[i1 * 16], 1);          // 64B-padded counters
        tokslot[i1 * 2048 + p1] = t; wroute[i1 * 2048 + p1] = ex[i1] * inv;
        int p2 = atomicAdd(&cnt[i2 * 16], 1);
        tokslot[i2 * 2048 + p2] = t; wroute[i2 * 2048 + p2] = ex[i2] * inv;
    }
    reinterpret_cast<float4*>(out + (size_t)t * 1024)[tid] = (float4){0.f, 0.f, 0.f, 0.f};
}

// ---------- unified fc1: 10 experts (8 routed + 2 shared pseudo), M128 x N64, BK=64 ---
// Grid 864 = 72 mt-slots x 12 ht. XCD swizzle: each mt's 12 ht-tiles on one XCD.
__global__ __launch_bounds__(256) void k_fc1u(const unsigned short* __restrict__ xb,
                                              const unsigned short* __restrict__ W1b,
                                              const unsigned short* __restrict__ Ws1b,
                                              const int* __restrict__ tokslot,
                                              const float* __restrict__ wroute,
                                              const int* __restrict__ cnt,
                                              unsigned short* __restrict__ act_r,
                                              unsigned short* __restrict__ acts) {
    __shared__ alignas(16) unsigned short As[128 * 64];   // 16KB
    __shared__ alignas(16) unsigned short Bs[128 * 64];   // 16KB: rows 0..63 y, 64..127 g
    const int tid = threadIdx.x, lane = tid & 63, w = tid >> 6;
    const int wr = w >> 1, wc = w & 1;
    // mt-granular XCD swizzle: bid%8 = XCD; j=bid/8 in [0,108); mt = (j/12)*8 + xcd.
    const int xcd = blockIdx.x & 7, j = blockIdx.x >> 3;
    const int mt = (j / 12) * 8 + xcd, ht = j % 12;

    int pre = 0, sel = -1, base = 0;
    for (int ee = 0; ee < 10; ee++) {
        int til = (ee < 8) ? ((cnt[ee * 16] + 127) >> 7) : 16;
        if (sel < 0 && mt < pre + til) { sel = ee; base = pre; }
        pre += til;
    }
    if (sel < 0) return;
    const int e = sel, m0 = (mt - base) * 128, h0 = ht * 64;
    const int Te = (e < 8) ? cnt[e * 16] : 2048;
    const unsigned short* Bp = (e < 8) ? (W1b + (size_t)e * 1536 * 1024)
                                       : (Ws1b + (size_t)(e - 8) * 768 * 1024);
    const int gOff = (e < 8) ? 768 : 1536;

    const int kc = tid & 7;
    int aoff[4], boff[4];
    for (int q = 0; q < 4; q++) {
        int row = q * 32 + (tid >> 3);                 // 0..127
        int idx = m0 + row;
        int tk = (e < 8) ? ((idx < Te) ? tokslot[e * 2048 + idx] : 0) : idx;
        aoff[q] = tk * 1024 + ((kc ^ (row & 7)) << 3);
        int grow = (row < 64) ? (h0 + row) : (gOff + h0 + row - 64);
        boff[q] = grow * 1024 + ((kc ^ (row & 7)) << 3);
    }

    f32x4 accy[4][2], accg[4][2];
    for (int i = 0; i < 4; i++)
        for (int j2 = 0; j2 < 2; j2++) {
            accy[i][j2] = (f32x4){0.f, 0.f, 0.f, 0.f};
            accg[i][j2] = (f32x4){0.f, 0.f, 0.f, 0.f};
        }

    for (int k0 = 0; k0 < 1024; k0 += 64) {
        for (int q = 0; q < 4; q++) {
            ldst16(xb + aoff[q] + k0, As + (q * 256 + tid) * 8);
            ldst16(Bp + boff[q] + k0, Bs + (q * 256 + tid) * 8);
        }
        __syncthreads();
        for (int kh = 0; kh < 2; kh++) {
            const int cq = kh * 4 + (lane >> 4);
            bf16x8 a[4], by[2], bg[2];
            for (int i = 0; i < 4; i++) {
                int r = 64 * wr + 16 * i + (lane & 15);
                a[i] = *(const bf16x8*)&As[r * 64 + ((cq ^ (r & 7)) << 3)];
            }
            for (int j2 = 0; j2 < 2; j2++) {
                int ry = 32 * wc + 16 * j2 + (lane & 15);
                by[j2] = *(const bf16x8*)&Bs[ry * 64 + ((cq ^ (ry & 7)) << 3)];
                int rg = 64 + ry;
                bg[j2] = *(const bf16x8*)&Bs[rg * 64 + ((cq ^ (rg & 7)) << 3)];
            }
            for (int i = 0; i < 4; i++)
                for (int j2 = 0; j2 < 2; j2++) {
                    accy[i][j2] = __builtin_amdgcn_mfma_f32_16x16x32_bf16(a[i], by[j2], accy[i][j2], 0, 0, 0);
                    accg[i][j2] = __builtin_amdgcn_mfma_f32_16x16x32_bf16(a[i], bg[j2], accg[i][j2], 0, 0, 0);
                }
        }
        __syncthreads();
    }

    for (int i = 0; i < 4; i++)
        for (int r = 0; r < 4; r++) {
            int irow = m0 + 64 * wr + 16 * i + ((lane >> 4) << 2) + r;
            if (irow >= Te) continue;
            float sw = (e < 8) ? wroute[e * 2048 + irow] : 1.0f;
            unsigned short* dst = (e < 8)
                ? (act_r + ((size_t)e * 2048 + irow) * 768)
                : (acts + (size_t)irow * 1536 + (size_t)(e - 8) * 768);
            for (int j2 = 0; j2 < 2; j2++) {
                float y = accy[i][j2][r], g = accg[i][j2][r];
                float sg = g / (1.0f + __expf(-g));
                int col = h0 + 32 * wc + 16 * j2 + (lane & 15);
                dst[col] = f2b(sw * y * sg);
            }
        }
}

// ------- unified fc2: routed (K=768) + shared (K=1536) tiles, atomicAdd into out ------
// M=128 x N=64, BK=128. Grid 896 = 56 mt-slots x 16 nt. LDS 48KB. XCD swizzle by mt.
__global__ __launch_bounds__(256) void k_fc2u(const unsigned short* __restrict__ act_r,
                                              const unsigned short* __restrict__ acts,
                                              const unsigned short* __restrict__ W2b,
                                              const unsigned short* __restrict__ Ws2b,
                                              const int* __restrict__ tokslot,
                                              const int* __restrict__ cnt,
                                              float* __restrict__ out) {
    __shared__ alignas(16) unsigned short As[128 * 128];  // 32KB
    __shared__ alignas(16) unsigned short Bs[64 * 128];   // 16KB
    const int tid = threadIdx.x, lane = tid & 63, w = tid >> 6;
    const int wr = w >> 1, wc = w & 1;
    // mt-granular XCD swizzle: bid%8 = XCD; j=bid/8 in [0,112); mt = (j/16)*8 + xcd.
    const int xcd = blockIdx.x & 7, j = blockIdx.x >> 3;
    const int mt = (j / 16) * 8 + xcd, nt = j % 16;

    int pre = 0, sel = -1, base = 0;
    for (int ee = 0; ee < 9; ee++) {
        int til = (ee < 8) ? ((cnt[ee * 16] + 127) >> 7) : 16;
        if (sel < 0 && mt < pre + til) { sel = ee; base = pre; }
        pre += til;
    }
    if (sel < 0) return;
    const int e = sel, m0 = (mt - base) * 128, n0 = nt * 64;
    int Te, astride, bstride, K;
    const unsigned short *Ab, *Bb;
    if (e < 8) {
        Te = cnt[e * 16]; K = 768; astride = 768; bstride = 768;
        Ab = act_r + (size_t)e * 2048 * 768;
        Bb = W2b + (size_t)e * 1024 * 768;
    } else {
        Te = 2048; K = 1536; astride = 1536; bstride = 1536;
        Ab = acts;
        Bb = Ws2b;
    }

    const int cp = tid & 15;
    int aoff[8], boff[4];
    for (int q = 0; q < 8; q++) {
        int row = q * 16 + (tid >> 4);                 // 0..127
        aoff[q] = (m0 + row) * astride + ((cp ^ (row & 15)) << 3);
    }
    for (int q = 0; q < 4; q++) {
        int row = q * 16 + (tid >> 4);                 // 0..63
        boff[q] = (n0 + row) * bstride + ((cp ^ (row & 15)) << 3);
    }

    f32x4 acc[4][2];
    for (int i = 0; i < 4; i++)
        for (int j2 = 0; j2 < 2; j2++) acc[i][j2] = (f32x4){0.f, 0.f, 0.f, 0.f};

    for (int k0 = 0; k0 < K; k0 += 128) {
        for (int q = 0; q < 8; q++) ldst16(Ab + aoff[q] + k0, As + (q * 256 + tid) * 8);
        for (int q = 0; q < 4; q++) ldst16(Bb + boff[q] + k0, Bs + (q * 256 + tid) * 8);
        __syncthreads();
        for (int kh = 0; kh < 4; kh++) {
            const int cq = kh * 4 + (lane >> 4);
            bf16x8 a[4], b[2];
            for (int i = 0; i < 4; i++) {
                int r = 64 * wr + 16 * i + (lane & 15);
                a[i] = *(const bf16x8*)&As[r * 128 + ((cq ^ (r & 15)) << 3)];
            }
            for (int j2 = 0; j2 < 2; j2++) {
                int rb = 32 * wc + 16 * j2 + (lane & 15);
                b[j2] = *(const bf16x8*)&Bs[rb * 128 + ((cq ^ (rb & 15)) << 3)];
            }
            for (int i = 0; i < 4; i++)
                for (int j2 = 0; j2 < 2; j2++)
                    acc[i][j2] = __builtin_amdgcn_mfma_f32_16x16x32_bf16(a[i], b[j2], acc[i][j2], 0, 0, 0);
        }
        __syncthreads();
    }

    for (int i = 0; i < 4; i++)
        for (int r = 0; r < 4; r++) {
            int irow = m0 + 64 * wr + 16 * i + ((lane >> 4) << 2) + r;
            if (irow >= Te) continue;
            int t = (e < 8) ? tokslot[e * 2048 + irow] : irow;
            for (int j2 = 0; j2 < 2; j2++) {
                int col = n0 + 32 * wc + 16 * j2 + (lane & 15);
                atomicAdd(out + (size_t)t * 1024 + col, acc[i][j2][r]);
            }
        }
}

extern "C" void kernel_launch(void* const* d_in, const int* in_sizes, int n_in,
                              void* d_out, int out_size, void* d_ws, size_t ws_size,
                              hipStream_t stream) {
    const float* x   = (const float*)d_in[0];
    const float* gw  = (const float*)d_in[1];
    const float* W1  = (const float*)d_in[2];
    const float* W2  = (const float*)d_in[3];
    const float* Ws1 = (const float*)d_in[4];
    const float* Ws2 = (const float*)d_in[5];
    float* out = (float*)d_out;

    char* ws = (char*)d_ws;
    unsigned short* xb    = (unsigned short*)(ws + 0);          //  4,194,304
    unsigned short* W1b   = (unsigned short*)(ws + 4194304);    // 25,165,824
    unsigned short* Ws1b  = (unsigned short*)(ws + 29360128);   //  6,291,456
    unsigned short* W2b   = (unsigned short*)(ws + 35651584);   // 12,582,912
    unsigned short* Ws2b  = (unsigned short*)(ws + 48234496);   //  3,145,728
    unsigned short* act_r = (unsigned short*)(ws + 51380224);   // 25,165,824 (8x2048x768)
    unsigned short* acts  = (unsigned short*)(ws + 76546048);   //  6,291,456 (2048x1536)
    int*            tokslot = (int*)(ws + 82837504);            //     65,536 (8x2048)
    float*          wroute  = (float*)(ws + 82903040);          //     65,536
    int*            cnt     = (int*)(ws + 82968576);            //        512 (8x16 ints)

    hipMemsetAsync(cnt, 0, 512, stream);
    k_convgate<<<7808, 256, 0, stream>>>(x, gw, W1, Ws1, W2, Ws2,
                                         xb, W1b, Ws1b, W2b, Ws2b,
                                         tokslot, wroute, cnt, out);
    k_fc1u<<<864, 256, 0, stream>>>(xb, W1b, Ws1b, tokslot, wroute, cnt, act_r, acts);
    k_fc2u<<<896, 256, 0, stream>>>(act_r, acts, W2b, Ws2b, tokslot, cnt, out);
}

// Round 5
// 238.386 us; speedup vs baseline: 1.8606x; 1.0235x over previous
//
#include <hip/hip_runtime.h>
#include <hip/hip_bf16.h>

// Sparse MoE: T=2048, D=1024, E=8 routed (H=768, top-2) + shared GatedMLP (1536 hidden).
// R11b (resubmit; R11 bench was an infra failure, no measurement): DELETE the weight-
// conversion pass. fc1/fc2 stage B directly from fp32 weights (global_load float4 x2 ->
// pack bf16x8 -> ds_write_b128 into the same XOR-swizzled LDS slots). A-operands
// (xb / act) stay bf16 via global_load_lds. A tiny k_gate keeps x->bf16, routing,
// out-zero. Removes ~143MB of pure format traffic + one dispatch + the fc1->W2-
// conversion false dependency. GEMM tile shapes/inner loops/epilogues are the proven
// R0 forms. (R10: XCD swizzle + 2-chunk conv both regressed, reverted. R9: coop
// mega-kernel regressed 2x, dead.)

typedef short bf16x8 __attribute__((ext_vector_type(8)));
typedef float f32x4 __attribute__((ext_vector_type(4)));

__device__ __forceinline__ unsigned short f2b(float f) {
    __hip_bfloat16 h = __float2bfloat16(f);
    return *reinterpret_cast<unsigned short*>(&h);
}

__device__ __forceinline__ void ldst16(const unsigned short* g, unsigned short* l) {
    __builtin_amdgcn_global_load_lds(
        (const __attribute__((address_space(1))) unsigned int*)g,
        (__attribute__((address_space(3))) unsigned int*)l, 16, 0, 0);
}

// 8 fp32 -> 8 bf16 packed in a uint4 (compiler fuses scalar casts to v_cvt_pk_bf16_f32)
__device__ __forceinline__ uint4 pack8(float4 a, float4 b) {
    union { unsigned short u[8]; uint4 v; } o;
    o.u[0]=f2b(a.x); o.u[1]=f2b(a.y); o.u[2]=f2b(a.z); o.u[3]=f2b(a.w);
    o.u[4]=f2b(b.x); o.u[5]=f2b(b.y); o.u[6]=f2b(b.z); o.u[7]=f2b(b.w);
    return o.v;
}

// ---------------- gate: one token per block; x->bf16, routing, out-zero -------------
__global__ __launch_bounds__(256) void k_gate(const float* __restrict__ x,
                                              const float* __restrict__ gw,
                                              unsigned short* __restrict__ xb,
                                              int* __restrict__ tokslot,
                                              float* __restrict__ wroute,
                                              int* __restrict__ cnt,
                                              float* __restrict__ out) {
    __shared__ float red[4][8];
    __shared__ float sc[8];
    const int t = blockIdx.x, tid = threadIdx.x;
    const int lane = tid & 63, w = tid >> 6;

    float4 v = reinterpret_cast<const float4*>(x + (size_t)t * 1024)[tid];
    union { unsigned short u[4]; ushort4 v4; } o;
    o.u[0]=f2b(v.x); o.u[1]=f2b(v.y); o.u[2]=f2b(v.z); o.u[3]=f2b(v.w);
    reinterpret_cast<ushort4*>(xb + (size_t)t * 1024)[tid] = o.v4;

    float p[8];
    for (int e = 0; e < 8; e++) {
        float4 g = reinterpret_cast<const float4*>(gw + (size_t)e * 1024)[tid];
        p[e] = v.x*g.x + v.y*g.y + v.z*g.z + v.w*g.w;
    }
    for (int e = 0; e < 8; e++)
        for (int off = 32; off > 0; off >>= 1) p[e] += __shfl_down(p[e], off, 64);
    if (lane == 0)
        for (int e = 0; e < 8; e++) red[w][e] = p[e];
    __syncthreads();
    if (tid < 8) sc[tid] = red[0][tid] + red[1][tid] + red[2][tid] + red[3][tid];
    __syncthreads();
    if (tid == 0) {
        float m = sc[0];
        for (int e = 1; e < 8; e++) m = fmaxf(m, sc[e]);
        float ex[8], sum = 0.f;
        for (int e = 0; e < 8; e++) { ex[e] = expf(sc[e] - m); sum += ex[e]; }
        float inv = 1.f / sum;
        int i1 = 0;
        for (int e = 1; e < 8; e++) if (sc[e] > sc[i1]) i1 = e;
        int i2 = -1; float s2 = -1e30f;
        for (int e = 0; e < 8; e++) if (e != i1 && sc[e] > s2) { s2 = sc[e]; i2 = e; }
        int p1 = atomicAdd(&cnt[i1 * 16], 1);          // 64B-padded counters
        tokslot[i1 * 2048 + p1] = t; wroute[i1 * 2048 + p1] = ex[i1] * inv;
        int p2 = atomicAdd(&cnt[i2 * 16], 1);
        tokslot[i2 * 2048 + p2] = t; wroute[i2 * 2048 + p2] = ex[i2] * inv;
    }
    reinterpret_cast<float4*>(out + (size_t)t * 1024)[tid] = (float4){0.f, 0.f, 0.f, 0.f};
}

// ---------- unified fc1: 10 experts (8 routed + 2 shared pseudo), M128 x N64, BK=64 ---
// Grid 864 = 72 mt-slots x 12 ht. A: bf16 xb via global_load_lds. B: fp32 W1/Ws1
// reg-staged (load->pack->ds_write) into the same XOR-swizzled slots.
__global__ __launch_bounds__(256) void k_fc1u(const unsigned short* __restrict__ xb,
                                              const float* __restrict__ W1f,
                                              const float* __restrict__ Ws1f,
                                              const int* __restrict__ tokslot,
                                              const float* __restrict__ wroute,
                                              const int* __restrict__ cnt,
                                              unsigned short* __restrict__ act_r,
                                              unsigned short* __restrict__ acts) {
    __shared__ alignas(16) unsigned short As[128 * 64];   // 16KB
    __shared__ alignas(16) unsigned short Bs[128 * 64];   // 16KB: rows 0..63 y, 64..127 g
    const int tid = threadIdx.x, lane = tid & 63, w = tid >> 6;
    const int wr = w >> 1, wc = w & 1;
    const int mt = blockIdx.x / 12, ht = blockIdx.x % 12;

    int pre = 0, sel = -1, base = 0;
    for (int ee = 0; ee < 10; ee++) {
        int til = (ee < 8) ? ((cnt[ee * 16] + 127) >> 7) : 16;
        if (sel < 0 && mt < pre + til) { sel = ee; base = pre; }
        pre += til;
    }
    if (sel < 0) return;
    const int e = sel, m0 = (mt - base) * 128, h0 = ht * 64;
    const int Te = (e < 8) ? cnt[e * 16] : 2048;
    const float* Bpf = (e < 8) ? (W1f + (size_t)e * 1536 * 1024)
                               : (Ws1f + (size_t)(e - 8) * 768 * 1024);
    const int gOff = (e < 8) ? 768 : 1536;

    const int kc = tid & 7;
    int aoff[4], boff[4];
    for (int q = 0; q < 4; q++) {
        int row = q * 32 + (tid >> 3);                 // 0..127
        int idx = m0 + row;
        int tk = (e < 8) ? ((idx < Te) ? tokslot[e * 2048 + idx] : 0) : idx;
        aoff[q] = tk * 1024 + ((kc ^ (row & 7)) << 3);
        int grow = (row < 64) ? (h0 + row) : (gOff + h0 + row - 64);
        boff[q] = grow * 1024 + ((kc ^ (row & 7)) << 3);
    }

    f32x4 accy[4][2], accg[4][2];
    for (int i = 0; i < 4; i++)
        for (int j = 0; j < 2; j++) {
            accy[i][j] = (f32x4){0.f, 0.f, 0.f, 0.f};
            accg[i][j] = (f32x4){0.f, 0.f, 0.f, 0.f};
        }

    for (int k0 = 0; k0 < 1024; k0 += 64) {
        for (int q = 0; q < 4; q++)
            ldst16(xb + aoff[q] + k0, As + (q * 256 + tid) * 8);
        #pragma unroll
        for (int q = 0; q < 4; q++) {
            float4 b0 = *reinterpret_cast<const float4*>(Bpf + boff[q] + k0);
            float4 b1 = *reinterpret_cast<const float4*>(Bpf + boff[q] + k0 + 4);
            *reinterpret_cast<uint4*>(&Bs[(q * 256 + tid) * 8]) = pack8(b0, b1);
        }
        __syncthreads();
        for (int kh = 0; kh < 2; kh++) {
            const int cq = kh * 4 + (lane >> 4);
            bf16x8 a[4], by[2], bg[2];
            for (int i = 0; i < 4; i++) {
                int r = 64 * wr + 16 * i + (lane & 15);
                a[i] = *(const bf16x8*)&As[r * 64 + ((cq ^ (r & 7)) << 3)];
            }
            for (int j = 0; j < 2; j++) {
                int ry = 32 * wc + 16 * j + (lane & 15);
                by[j] = *(const bf16x8*)&Bs[ry * 64 + ((cq ^ (ry & 7)) << 3)];
                int rg = 64 + ry;
                bg[j] = *(const bf16x8*)&Bs[rg * 64 + ((cq ^ (rg & 7)) << 3)];
            }
            for (int i = 0; i < 4; i++)
                for (int j = 0; j < 2; j++) {
                    accy[i][j] = __builtin_amdgcn_mfma_f32_16x16x32_bf16(a[i], by[j], accy[i][j], 0, 0, 0);
                    accg[i][j] = __builtin_amdgcn_mfma_f32_16x16x32_bf16(a[i], bg[j], accg[i][j], 0, 0, 0);
                }
        }
        __syncthreads();
    }

    for (int i = 0; i < 4; i++)
        for (int r = 0; r < 4; r++) {
            int irow = m0 + 64 * wr + 16 * i + ((lane >> 4) << 2) + r;
            if (irow >= Te) continue;
            float sw = (e < 8) ? wroute[e * 2048 + irow] : 1.0f;
            unsigned short* dst = (e < 8)
                ? (act_r + ((size_t)e * 2048 + irow) * 768)
                : (acts + (size_t)irow * 1536 + (size_t)(e - 8) * 768);
            for (int j = 0; j < 2; j++) {
                float y = accy[i][j][r], g = accg[i][j][r];
                float sg = g / (1.0f + __expf(-g));
                int col = h0 + 32 * wc + 16 * j + (lane & 15);
                dst[col] = f2b(sw * y * sg);
            }
        }
}

// ------- unified fc2: routed (K=768) + shared (K=1536) tiles, atomicAdd into out ------
// M=128 x N=64, BK=128. Grid 896 = 56 mt-slots x 16 nt. LDS 48KB.
// A: bf16 act via global_load_lds. B: fp32 W2/Ws2 reg-staged.
__global__ __launch_bounds__(256) void k_fc2u(const unsigned short* __restrict__ act_r,
                                              const unsigned short* __restrict__ acts,
                                              const float* __restrict__ W2f,
                                              const float* __restrict__ Ws2f,
                                              const int* __restrict__ tokslot,
                                              const int* __restrict__ cnt,
                                              float* __restrict__ out) {
    __shared__ alignas(16) unsigned short As[128 * 128];  // 32KB
    __shared__ alignas(16) unsigned short Bs[64 * 128];   // 16KB
    const int tid = threadIdx.x, lane = tid & 63, w = tid >> 6;
    const int wr = w >> 1, wc = w & 1;
    const int mt = blockIdx.x >> 4, nt = blockIdx.x & 15;

    int pre = 0, sel = -1, base = 0;
    for (int ee = 0; ee < 9; ee++) {
        int til = (ee < 8) ? ((cnt[ee * 16] + 127) >> 7) : 16;
        if (sel < 0 && mt < pre + til) { sel = ee; base = pre; }
        pre += til;
    }
    if (sel < 0) return;
    const int e = sel, m0 = (mt - base) * 128, n0 = nt * 64;
    int Te, astride, bstride, K;
    const unsigned short *Ab;
    const float *Bbf;
    if (e < 8) {
        Te = cnt[e * 16]; K = 768; astride = 768; bstride = 768;
        Ab = act_r + (size_t)e * 2048 * 768;
        Bbf = W2f + (size_t)e * 1024 * 768;
    } else {
        Te = 2048; K = 1536; astride = 1536; bstride = 1536;
        Ab = acts;
        Bbf = Ws2f;
    }

    const int cp = tid & 15;
    int aoff[8], boff[4];
    for (int q = 0; q < 8; q++) {
        int row = q * 16 + (tid >> 4);                 // 0..127
        aoff[q] = (m0 + row) * astride + ((cp ^ (row & 15)) << 3);
    }
    for (int q = 0; q < 4; q++) {
        int row = q * 16 + (tid >> 4);                 // 0..63
        boff[q] = (n0 + row) * bstride + ((cp ^ (row & 15)) << 3);
    }

    f32x4 acc[4][2];
    for (int i = 0; i < 4; i++)
        for (int j = 0; j < 2; j++) acc[i][j] = (f32x4){0.f, 0.f, 0.f, 0.f};

    for (int k0 = 0; k0 < K; k0 += 128) {
        for (int q = 0; q < 8; q++)
            ldst16(Ab + aoff[q] + k0, As + (q * 256 + tid) * 8);
        #pragma unroll
        for (int q = 0; q < 4; q++) {
            float4 b0 = *reinterpret_cast<const float4*>(Bbf + boff[q] + k0);
            float4 b1 = *reinterpret_cast<const float4*>(Bbf + boff[q] + k0 + 4);
            *reinterpret_cast<uint4*>(&Bs[(q * 256 + tid) * 8]) = pack8(b0, b1);
        }
        __syncthreads();
        for (int kh = 0; kh < 4; kh++) {
            const int cq = kh * 4 + (lane >> 4);
            bf16x8 a[4], b[2];
            for (int i = 0; i < 4; i++) {
                int r = 64 * wr + 16 * i + (lane & 15);
                a[i] = *(const bf16x8*)&As[r * 128 + ((cq ^ (r & 15)) << 3)];
            }
            for (int j = 0; j < 2; j++) {
                int rb = 32 * wc + 16 * j + (lane & 15);
                b[j] = *(const bf16x8*)&Bs[rb * 128 + ((cq ^ (rb & 15)) << 3)];
            }
            for (int i = 0; i < 4; i++)
                for (int j = 0; j < 2; j++)
                    acc[i][j] = __builtin_amdgcn_mfma_f32_16x16x32_bf16(a[i], b[j], acc[i][j], 0, 0, 0);
        }
        __syncthreads();
    }

    for (int i = 0; i < 4; i++)
        for (int r = 0; r < 4; r++) {
            int irow = m0 + 64 * wr + 16 * i + ((lane >> 4) << 2) + r;
            if (irow >= Te) continue;
            int t = (e < 8) ? tokslot[e * 2048 + irow] : irow;
            for (int j = 0; j < 2; j++) {
                int col = n0 + 32 * wc + 16 * j + (lane & 15);
                atomicAdd(out + (size_t)t * 1024 + col, acc[i][j][r]);
            }
        }
}

extern "C" void kernel_launch(void* const* d_in, const int* in_sizes, int n_in,
                              void* d_out, int out_size, void* d_ws, size_t ws_size,
                              hipStream_t stream) {
    const float* x   = (const float*)d_in[0];
    const float* gw  = (const float*)d_in[1];
    const float* W1  = (const float*)d_in[2];
    const float* W2  = (const float*)d_in[3];
    const float* Ws1 = (const float*)d_in[4];
    const float* Ws2 = (const float*)d_in[5];
    float* out = (float*)d_out;

    char* ws = (char*)d_ws;
    unsigned short* xb    = (unsigned short*)(ws + 0);          //  4,194,304
    unsigned short* act_r = (unsigned short*)(ws + 4194304);    // 25,165,824 (8x2048x768)
    unsigned short* acts  = (unsigned short*)(ws + 29360128);   //  6,291,456 (2048x1536)
    int*            tokslot = (int*)(ws + 35651584);            //     65,536 (8x2048)
    float*          wroute  = (float*)(ws + 35717120);          //     65,536
    int*            cnt     = (int*)(ws + 35782656);            //        512 (8x16 ints)

    hipMemsetAsync(cnt, 0, 512, stream);
    k_gate<<<2048, 256, 0, stream>>>(x, gw, xb, tokslot, wroute, cnt, out);
    k_fc1u<<<864, 256, 0, stream>>>(xb, W1, Ws1, tokslot, wroute, cnt, act_r, acts);
    k_fc2u<<<896, 256, 0, stream>>>(act_r, acts, W2, Ws2, tokslot, cnt, out);
}

// Round 6
// 233.917 us; speedup vs baseline: 1.8962x; 1.0191x over previous
//
#include <hip/hip_runtime.h>
#include <hip/hip_bf16.h>

// Sparse MoE: T=2048, D=1024, E=8 routed (H=768, top-2) + shared GatedMLP (1536 hidden).
// R12: keep bf16 pre-conversion (R11b proved L3-warm bf16 weights beat fp32-direct
// staging), but break the false dependency: W2/Ws2 conversion (3840 streaming blocks,
// 38MB) rides INSIDE the fc1 dispatch (bids >= 864), filling fc1's idle CU slots
// (864 fc1 tiles = 3.4 blocks/CU, all co-resident; 1.3 TB/s leaves BW headroom).
// convgate now converts only W1/Ws1 (+gate): ~2/3 traffic. fc2 unchanged (R0 form).
// GEMM tile bodies = R0 proven forms + s_setprio around MFMA (phase-staggered blocks,
// not lockstep). R8-R11 ledger: dbuf ~neutral, XCD swizzle regressed, mega-kernel 2x
// regressed, fp32-direct regressed fc1 +22us.

typedef short bf16x8 __attribute__((ext_vector_type(8)));
typedef float f32x4 __attribute__((ext_vector_type(4)));

__device__ __forceinline__ unsigned short f2b(float f) {
    __hip_bfloat16 h = __float2bfloat16(f);
    return *reinterpret_cast<unsigned short*>(&h);
}

__device__ __forceinline__ void ldst16(const unsigned short* g, unsigned short* l) {
    __builtin_amdgcn_global_load_lds(
        (const __attribute__((address_space(1))) unsigned int*)g,
        (__attribute__((address_space(3))) unsigned int*)l, 16, 0, 0);
}

__device__ __forceinline__ void cvt8(const float* s, unsigned short* d, int j) {
    const float4* sp = reinterpret_cast<const float4*>(s) + (size_t)j * 2;
    float4 v0 = sp[0], v1 = sp[1];
    union { unsigned short u[8]; uint4 v; } o;
    o.u[0]=f2b(v0.x); o.u[1]=f2b(v0.y); o.u[2]=f2b(v0.z); o.u[3]=f2b(v0.w);
    o.u[4]=f2b(v1.x); o.u[5]=f2b(v1.y); o.u[6]=f2b(v1.z); o.u[7]=f2b(v1.w);
    *(reinterpret_cast<uint4*>(d) + j) = o.v;
}

// ------- convgate: W1/Ws1 conversion (blocks 0..7679) + gate (blocks 7680..9727) -----
__global__ __launch_bounds__(256) void k_convgate(const float* __restrict__ x,
                                                  const float* __restrict__ gw,
                                                  const float* __restrict__ W1,
                                                  const float* __restrict__ Ws1,
                                                  unsigned short* __restrict__ xb,
                                                  unsigned short* __restrict__ W1b,
                                                  unsigned short* __restrict__ Ws1b,
                                                  int* __restrict__ tokslot,
                                                  float* __restrict__ wroute,
                                                  int* __restrict__ cnt,
                                                  float* __restrict__ out) {
    __shared__ float red[4][8];
    __shared__ float sc[8];
    const int b = blockIdx.x, tid = threadIdx.x;
    if (b < 7680) {
        int i = b * 256 + tid;
        if (i < 1572864)  cvt8(W1,  W1b,  i);            // 8x1536x1024/8 chunks
        else              cvt8(Ws1, Ws1b, i - 1572864);  // 2x1536x1024/8 chunks
        return;
    }
    // ---- gate: one token per block, fully coalesced ----
    const int t = b - 7680;
    const int lane = tid & 63, w = tid >> 6;

    float4 v = reinterpret_cast<const float4*>(x + (size_t)t * 1024)[tid];
    union { unsigned short u[4]; ushort4 v4; } o;
    o.u[0]=f2b(v.x); o.u[1]=f2b(v.y); o.u[2]=f2b(v.z); o.u[3]=f2b(v.w);
    reinterpret_cast<ushort4*>(xb + (size_t)t * 1024)[tid] = o.v4;

    float p[8];
    for (int e = 0; e < 8; e++) {
        float4 g = reinterpret_cast<const float4*>(gw + (size_t)e * 1024)[tid];
        p[e] = v.x*g.x + v.y*g.y + v.z*g.z + v.w*g.w;
    }
    for (int e = 0; e < 8; e++)
        for (int off = 32; off > 0; off >>= 1) p[e] += __shfl_down(p[e], off, 64);
    if (lane == 0)
        for (int e = 0; e < 8; e++) red[w][e] = p[e];
    __syncthreads();
    if (tid < 8) sc[tid] = red[0][tid] + red[1][tid] + red[2][tid] + red[3][tid];
    __syncthreads();
    if (tid == 0) {
        float m = sc[0];
        for (int e = 1; e < 8; e++) m = fmaxf(m, sc[e]);
        float ex[8], sum = 0.f;
        for (int e = 0; e < 8; e++) { ex[e] = expf(sc[e] - m); sum += ex[e]; }
        float inv = 1.f / sum;
        int i1 = 0;
        for (int e = 1; e < 8; e++) if (sc[e] > sc[i1]) i1 = e;
        int i2 = -1; float s2 = -1e30f;
        for (int e = 0; e < 8; e++) if (e != i1 && sc[e] > s2) { s2 = sc[e]; i2 = e; }
        int p1 = atomicAdd(&cnt[i1 * 16], 1);          // 64B-padded counters
        tokslot[i1 * 2048 + p1] = t; wroute[i1 * 2048 + p1] = ex[i1] * inv;
        int p2 = atomicAdd(&cnt[i2 * 16], 1);
        tokslot[i2 * 2048 + p2] = t; wroute[i2 * 2048 + p2] = ex[i2] * inv;
    }
    reinterpret_cast<float4*>(out + (size_t)t * 1024)[tid] = (float4){0.f, 0.f, 0.f, 0.f};
}

// ---------- fc1 (bids 0..863) + W2/Ws2 conversion (bids 864..4703) -------------------
// fc1: 10 experts (8 routed + 2 shared pseudo), M128 x (N64y|N64g), BK=64, R0 form.
// Conv blocks stream 38MB of W2/Ws2 fp32->bf16 in fc1's idle CU slots / BW headroom.
__global__ __launch_bounds__(256) void k_fc1w(const unsigned short* __restrict__ xb,
                                              const unsigned short* __restrict__ W1b,
                                              const unsigned short* __restrict__ Ws1b,
                                              const float* __restrict__ W2,
                                              const float* __restrict__ Ws2,
                                              unsigned short* __restrict__ W2b,
                                              unsigned short* __restrict__ Ws2b,
                                              const int* __restrict__ tokslot,
                                              const float* __restrict__ wroute,
                                              const int* __restrict__ cnt,
                                              unsigned short* __restrict__ act_r,
                                              unsigned short* __restrict__ acts) {
    __shared__ alignas(16) unsigned short As[128 * 64];   // 16KB
    __shared__ alignas(16) unsigned short Bs[128 * 64];   // 16KB: rows 0..63 y, 64..127 g
    const int tid = threadIdx.x;
    if (blockIdx.x >= 864) {
        int i = (blockIdx.x - 864) * 256 + tid;
        if (i < 786432)  cvt8(W2,  W2b,  i);             // 8x1024x768/8 chunks
        else             cvt8(Ws2, Ws2b, i - 786432);    // 1024x1536/8 chunks
        return;
    }
    const int lane = tid & 63, w = tid >> 6;
    const int wr = w >> 1, wc = w & 1;
    const int mt = blockIdx.x / 12, ht = blockIdx.x % 12;

    int pre = 0, sel = -1, base = 0;
    for (int ee = 0; ee < 10; ee++) {
        int til = (ee < 8) ? ((cnt[ee * 16] + 127) >> 7) : 16;
        if (sel < 0 && mt < pre + til) { sel = ee; base = pre; }
        pre += til;
    }
    if (sel < 0) return;
    const int e = sel, m0 = (mt - base) * 128, h0 = ht * 64;
    const int Te = (e < 8) ? cnt[e * 16] : 2048;
    const unsigned short* Bp = (e < 8) ? (W1b + (size_t)e * 1536 * 1024)
                                       : (Ws1b + (size_t)(e - 8) * 768 * 1024);
    const int gOff = (e < 8) ? 768 : 1536;

    const int kc = tid & 7;
    int aoff[4], boff[4];
    for (int q = 0; q < 4; q++) {
        int row = q * 32 + (tid >> 3);                 // 0..127
        int idx = m0 + row;
        int tk = (e < 8) ? ((idx < Te) ? tokslot[e * 2048 + idx] : 0) : idx;
        aoff[q] = tk * 1024 + ((kc ^ (row & 7)) << 3);
        int grow = (row < 64) ? (h0 + row) : (gOff + h0 + row - 64);
        boff[q] = grow * 1024 + ((kc ^ (row & 7)) << 3);
    }

    f32x4 accy[4][2], accg[4][2];
    for (int i = 0; i < 4; i++)
        for (int j = 0; j < 2; j++) {
            accy[i][j] = (f32x4){0.f, 0.f, 0.f, 0.f};
            accg[i][j] = (f32x4){0.f, 0.f, 0.f, 0.f};
        }

    for (int k0 = 0; k0 < 1024; k0 += 64) {
        for (int q = 0; q < 4; q++) {
            ldst16(xb + aoff[q] + k0, As + (q * 256 + tid) * 8);
            ldst16(Bp + boff[q] + k0, Bs + (q * 256 + tid) * 8);
        }
        __syncthreads();
        for (int kh = 0; kh < 2; kh++) {
            const int cq = kh * 4 + (lane >> 4);
            bf16x8 a[4], by[2], bg[2];
            for (int i = 0; i < 4; i++) {
                int r = 64 * wr + 16 * i + (lane & 15);
                a[i] = *(const bf16x8*)&As[r * 64 + ((cq ^ (r & 7)) << 3)];
            }
            for (int j = 0; j < 2; j++) {
                int ry = 32 * wc + 16 * j + (lane & 15);
                by[j] = *(const bf16x8*)&Bs[ry * 64 + ((cq ^ (ry & 7)) << 3)];
                int rg = 64 + ry;
                bg[j] = *(const bf16x8*)&Bs[rg * 64 + ((cq ^ (rg & 7)) << 3)];
            }
            __builtin_amdgcn_s_setprio(1);
            for (int i = 0; i < 4; i++)
                for (int j = 0; j < 2; j++) {
                    accy[i][j] = __builtin_amdgcn_mfma_f32_16x16x32_bf16(a[i], by[j], accy[i][j], 0, 0, 0);
                    accg[i][j] = __builtin_amdgcn_mfma_f32_16x16x32_bf16(a[i], bg[j], accg[i][j], 0, 0, 0);
                }
            __builtin_amdgcn_s_setprio(0);
        }
        __syncthreads();
    }

    for (int i = 0; i < 4; i++)
        for (int r = 0; r < 4; r++) {
            int irow = m0 + 64 * wr + 16 * i + ((lane >> 4) << 2) + r;
            if (irow >= Te) continue;
            float sw = (e < 8) ? wroute[e * 2048 + irow] : 1.0f;
            unsigned short* dst = (e < 8)
                ? (act_r + ((size_t)e * 2048 + irow) * 768)
                : (acts + (size_t)irow * 1536 + (size_t)(e - 8) * 768);
            for (int j = 0; j < 2; j++) {
                float y = accy[i][j][r], g = accg[i][j][r];
                float sg = g / (1.0f + __expf(-g));
                int col = h0 + 32 * wc + 16 * j + (lane & 15);
                dst[col] = f2b(sw * y * sg);
            }
        }
}

// ------- unified fc2: routed (K=768) + shared (K=1536) tiles, atomicAdd into out ------
// M=128 x N=64, BK=128. Grid 896 = 56 mt-slots x 16 nt. LDS 48KB. R0 form.
__global__ __launch_bounds__(256) void k_fc2u(const unsigned short* __restrict__ act_r,
                                              const unsigned short* __restrict__ acts,
                                              const unsigned short* __restrict__ W2b,
                                              const unsigned short* __restrict__ Ws2b,
                                              const int* __restrict__ tokslot,
                                              const int* __restrict__ cnt,
                                              float* __restrict__ out) {
    __shared__ alignas(16) unsigned short As[128 * 128];  // 32KB
    __shared__ alignas(16) unsigned short Bs[64 * 128];   // 16KB
    const int tid = threadIdx.x, lane = tid & 63, w = tid >> 6;
    const int wr = w >> 1, wc = w & 1;
    const int mt = blockIdx.x >> 4, nt = blockIdx.x & 15;

    int pre = 0, sel = -1, base = 0;
    for (int ee = 0; ee < 9; ee++) {
        int til = (ee < 8) ? ((cnt[ee * 16] + 127) >> 7) : 16;
        if (sel < 0 && mt < pre + til) { sel = ee; base = pre; }
        pre += til;
    }
    if (sel < 0) return;
    const int e = sel, m0 = (mt - base) * 128, n0 = nt * 64;
    int Te, astride, bstride, K;
    const unsigned short *Ab, *Bb;
    if (e < 8) {
        Te = cnt[e * 16]; K = 768; astride = 768; bstride = 768;
        Ab = act_r + (size_t)e * 2048 * 768;
        Bb = W2b + (size_t)e * 1024 * 768;
    } else {
        Te = 2048; K = 1536; astride = 1536; bstride = 1536;
        Ab = acts;
        Bb = Ws2b;
    }

    const int cp = tid & 15;
    int aoff[8], boff[4];
    for (int q = 0; q < 8; q++) {
        int row = q * 16 + (tid >> 4);                 // 0..127
        aoff[q] = (m0 + row) * astride + ((cp ^ (row & 15)) << 3);
    }
    for (int q = 0; q < 4; q++) {
        int row = q * 16 + (tid >> 4);                 // 0..63
        boff[q] = (n0 + row) * bstride + ((cp ^ (row & 15)) << 3);
    }

    f32x4 acc[4][2];
    for (int i = 0; i < 4; i++)
        for (int j = 0; j < 2; j++) acc[i][j] = (f32x4){0.f, 0.f, 0.f, 0.f};

    for (int k0 = 0; k0 < K; k0 += 128) {
        for (int q = 0; q < 8; q++) ldst16(Ab + aoff[q] + k0, As + (q * 256 + tid) * 8);
        for (int q = 0; q < 4; q++) ldst16(Bb + boff[q] + k0, Bs + (q * 256 + tid) * 8);
        __syncthreads();
        for (int kh = 0; kh < 4; kh++) {
            const int cq = kh * 4 + (lane >> 4);
            bf16x8 a[4], b[2];
            for (int i = 0; i < 4; i++) {
                int r = 64 * wr + 16 * i + (lane & 15);
                a[i] = *(const bf16x8*)&As[r * 128 + ((cq ^ (r & 15)) << 3)];
            }
            for (int j = 0; j < 2; j++) {
                int rb = 32 * wc + 16 * j + (lane & 15);
                b[j] = *(const bf16x8*)&Bs[rb * 128 + ((cq ^ (rb & 15)) << 3)];
            }
            __builtin_amdgcn_s_setprio(1);
            for (int i = 0; i < 4; i++)
                for (int j = 0; j < 2; j++)
                    acc[i][j] = __builtin_amdgcn_mfma_f32_16x16x32_bf16(a[i], b[j], acc[i][j], 0, 0, 0);
            __builtin_amdgcn_s_setprio(0);
        }
        __syncthreads();
    }

    for (int i = 0; i < 4; i++)
        for (int r = 0; r < 4; r++) {
            int irow = m0 + 64 * wr + 16 * i + ((lane >> 4) << 2) + r;
            if (irow >= Te) continue;
            int t = (e < 8) ? tokslot[e * 2048 + irow] : irow;
            for (int j = 0; j < 2; j++) {
                int col = n0 + 32 * wc + 16 * j + (lane & 15);
                atomicAdd(out + (size_t)t * 1024 + col, acc[i][j][r]);
            }
        }
}

extern "C" void kernel_launch(void* const* d_in, const int* in_sizes, int n_in,
                              void* d_out, int out_size, void* d_ws, size_t ws_size,
                              hipStream_t stream) {
    const float* x   = (const float*)d_in[0];
    const float* gw  = (const float*)d_in[1];
    const float* W1  = (const float*)d_in[2];
    const float* W2  = (const float*)d_in[3];
    const float* Ws1 = (const float*)d_in[4];
    const float* Ws2 = (const float*)d_in[5];
    float* out = (float*)d_out;

    char* ws = (char*)d_ws;
    unsigned short* xb    = (unsigned short*)(ws + 0);          //  4,194,304
    unsigned short* W1b   = (unsigned short*)(ws + 4194304);    // 25,165,824
    unsigned short* Ws1b  = (unsigned short*)(ws + 29360128);   //  6,291,456
    unsigned short* W2b   = (unsigned short*)(ws + 35651584);   // 12,582,912
    unsigned short* Ws2b  = (unsigned short*)(ws + 48234496);   //  3,145,728
    unsigned short* act_r = (unsigned short*)(ws + 51380224);   // 25,165,824 (8x2048x768)
    unsigned short* acts  = (unsigned short*)(ws + 76546048);   //  6,291,456 (2048x1536)
    int*            tokslot = (int*)(ws + 82837504);            //     65,536 (8x2048)
    float*          wroute  = (float*)(ws + 82903040);          //     65,536
    int*            cnt     = (int*)(ws + 82968576);            //        512 (8x16 ints)

    hipMemsetAsync(cnt, 0, 512, stream);
    k_convgate<<<9728, 256, 0, stream>>>(x, gw, W1, Ws1,
                                         xb, W1b, Ws1b,
                                         tokslot, wroute, cnt, out);
    k_fc1w<<<4704, 256, 0, stream>>>(xb, W1b, Ws1b, W2, Ws2, W2b, Ws2b,
                                     tokslot, wroute, cnt, act_r, acts);
    k_fc2u<<<896, 256, 0, stream>>>(act_r, acts, W2b, Ws2b, tokslot, cnt, out);
}